// Round 5
// baseline (672.542 us; speedup 1.0000x reference)
//
#include <hip/hip_runtime.h>
#include <stdint.h>

#define EMBED 1024
#define NH 16
#define HD 64
#define SEQ 2048
#define BATCH 4
#define M_TOT (BATCH*SEQ)   // 8192
#define QSCALE 0.18033688011112042f   // log2(e)/sqrt(HD)

typedef __attribute__((ext_vector_type(8))) short short8;
typedef __attribute__((ext_vector_type(4))) float floatx4;
typedef __attribute__((ext_vector_type(4))) unsigned int uintx4;

__device__ __forceinline__ unsigned short f2bf(float f) {
    union { float f; unsigned int u; } v; v.f = f;
    unsigned int r = v.u + 0x7fffu + ((v.u >> 16) & 1u);
    return (unsigned short)(r >> 16);
}

__device__ __forceinline__ void load_lds16(const unsigned short* g, unsigned short* l) {
    __builtin_amdgcn_global_load_lds(
        (const __attribute__((address_space(1))) unsigned int*)g,
        (__attribute__((address_space(3))) unsigned int*)l, 16, 0, 0);
}

// ---- kernel 1: x fp32 -> bf16 ----
__global__ void cvt_x(const float* __restrict__ x, unsigned short* __restrict__ xb) {
    int i = (blockIdx.x * 256 + threadIdx.x) * 4;
    float4 v = *(const float4*)(x + i);
    ushort4 o;
    o.x = f2bf(v.x); o.y = f2bf(v.y); o.z = f2bf(v.z); o.w = f2bf(v.w);
    *(ushort4*)(xb + i) = o;
}

// ---- kernel 2: transpose W [k][n] fp32 -> WT [n][k] bf16 ----
__global__ void wtrans(const float* __restrict__ w0, const float* __restrict__ w1,
                       const float* __restrict__ w2, const float* __restrict__ w3,
                       unsigned short* __restrict__ t0, unsigned short* __restrict__ t1,
                       unsigned short* __restrict__ t2, unsigned short* __restrict__ t3) {
    __shared__ float tile[32][33];
    const float* W; unsigned short* T;
    switch (blockIdx.z) { case 0: W=w0; T=t0; break; case 1: W=w1; T=t1; break;
                          case 2: W=w2; T=t2; break; default: W=w3; T=t3; }
    int n0 = blockIdx.x * 32, k0 = blockIdx.y * 32;
    int tx = threadIdx.x, ty = threadIdx.y;
    #pragma unroll
    for (int i = 0; i < 4; i++)
        tile[ty + i*8][tx] = W[(k0 + ty + i*8) * EMBED + n0 + tx];
    __syncthreads();
    #pragma unroll
    for (int i = 0; i < 4; i++)
        T[(n0 + ty + i*8) * EMBED + k0 + tx] = f2bf(tile[tx][ty + i*8]);
}

// ---- kernel 3: templated GEMM, BK=32, DOUBLE-buffered LDS sized for MULTI-BLOCK
// RESIDENCY (the round-4 lesson: 128KB LDS capped occupancy at 1 block/CU = 2
// waves/SIMD; every schedule variant was latency-exposed at that residency).
// C[M,N] = A[M,K] @ BT[N,K]^T + bias, K=1024 (32 K-tiles).
// Config QKV : MODE 0, BM=BN=256, NW=8 (2x4 waves, wave 128x64, acc[8][4]),
//              LDS 64KB -> 2 blocks/CU (16 waves/CU), launch_bounds(512,4) caps
//              VGPR at 128 (rounds 3/4 measured exactly 128 for this body).
// Config proj: MODE 1, BM=BN=128, NW=4 (2x2 waves, wave 64x64, acc[4][4]),
//              LDS 32KB -> 4 blocks/CU; grid 512 = every CU busy (round-4's 128
//              blocks left half the chip idle).
// LDS swizzle (BK=32): row r = 64B = 4 chunks of 16B; slot s holds logical chunk
// s^(r&3); inverse-swizzled global source (global_load_lds dest is linear), same
// XOR on ds_read. Schedule per tile t: {FM+FN ds_read_b128; stage t+1 -> buf^1
// (4 gloads); FMxFN MFMA; vmcnt(0); s_barrier}. Stage->wait gap = full MFMA
// phase; co-resident blocks cover the residual L2 latency. Buffer safety:
// stage(t+1) writes buf read at t-1, whose reads completed before barrier(t-1).
// Grid: id&7 = XCD stripe (A-stripe L2-resident).
template<int MODE, int BM, int BN, int NW>
__global__ __launch_bounds__(NW*64, 4) void gemmk(
        const unsigned short* __restrict__ A, const unsigned short* __restrict__ BT,
        const float* __restrict__ b0, const float* __restrict__ b1, const float* __restrict__ b2,
        void* __restrict__ o0, void* __restrict__ o1, void* __restrict__ o2) {
    constexpr int THREADS = NW*64;
    constexpr int WC = NW/2;            // wave grid 2 x WC
    constexpr int WMT = BM/2, WNT = BN/WC;
    constexpr int FM = WMT/16, FN = WNT/16;
    constexpr int RPI = THREADS/4;      // rows per staging issue (16B/thread)
    constexpr int BUFS = (BM+BN)*32;    // ushorts per buffer
    static_assert(BM == 2*RPI && BN == 2*RPI, "staging assumes 2 issues/operand");
    __shared__ unsigned short lds[2*BUFS];
    const int tid = threadIdx.x;
    const int lane = tid & 63, wave = tid >> 6;
    const int quad = lane >> 4, l16 = lane & 15;
    const int wm = wave / WC, wn = wave % WC;
    const int id = blockIdx.x;
    constexpr int MS = (M_TOT/BM)/8;    // m-blocks per XCD stripe
    const int xcd = id & 7, j = id >> 3;
    const int mblk = (xcd * MS + (j % MS)) * BM;
    const int nblk = (j / MS) * BN;

    // staging: thread tid covers (row tid>>2, slot tid&3); slot s loads logical
    // chunk s^(row&3) (inverse-swizzled source). Wave w's 64 lanes = 16 rows.
    const int srow = tid >> 2;
    const int scol = ((tid & 3) ^ (srow & 3)) * 8;
    const unsigned short* Asrc = A  + (size_t)(mblk + srow) * EMBED + scol;
    const unsigned short* Bsrc = BT + (size_t)(nblk + srow) * EMBED + scol;
    unsigned short* sda = lds + wave * 512;
    unsigned short* sdb = lds + BM*32 + wave * 512;

    // swizzled fragment-read base: row ..+l16, logical chunk quad at slot quad^(l16&3)
    const int cs = (quad ^ (l16 & 3)) * 8;
    const unsigned short* Abase = lds + (wm*WMT + l16)*32 + cs;
    const unsigned short* Bbase = lds + BM*32 + (wn*WNT + l16)*32 + cs;

    floatx4 acc[FM][FN];
    #pragma unroll
    for (int m=0;m<FM;m++)
      #pragma unroll
      for (int n=0;n<FN;n++) acc[m][n] = (floatx4){0.f,0.f,0.f,0.f};

#define ST(t_) do { \
    const int buf_ = (t_) & 1; const int ko_ = (t_)*32; \
    load_lds16(Asrc + ko_,              sda + buf_*BUFS); \
    load_lds16(Asrc + ko_ + RPI*EMBED,  sda + buf_*BUFS + RPI*32); \
    load_lds16(Bsrc + ko_,              sdb + buf_*BUFS); \
    load_lds16(Bsrc + ko_ + RPI*EMBED,  sdb + buf_*BUFS + RPI*32); \
  } while(0)

    ST(0);
    asm volatile("s_waitcnt vmcnt(0)" ::: "memory");
    asm volatile("s_barrier" ::: "memory");

    #pragma unroll 2
    for (int t = 0; t < 32; ++t) {
        const int bo = (t & 1) * BUFS;
        short8 fA[FM], fB[FN];
        #pragma unroll
        for (int m=0;m<FM;m++) fA[m] = *(const short8*)(Abase + bo + m*512);
        #pragma unroll
        for (int n=0;n<FN;n++) fB[n] = *(const short8*)(Bbase + bo + n*512);
        if (t < 31) ST(t+1);
        #pragma unroll
        for (int m=0;m<FM;m++)
          #pragma unroll
          for (int n=0;n<FN;n++)
            acc[m][n] = __builtin_amdgcn_mfma_f32_16x16x32_bf16(fA[m], fB[n], acc[m][n], 0,0,0);
        if (t < 31) asm volatile("s_waitcnt vmcnt(0)" ::: "memory");
        asm volatile("s_barrier" ::: "memory");
    }
#undef ST

    // epilogue: C/D layout col=lane&15, row=quad*4+reg
    if constexpr (MODE == 1) {
        float* O = (float*)o0;
        #pragma unroll
        for (int mt=0;mt<FM;mt++)
          #pragma unroll
          for (int nt=0;nt<FN;nt++) {
            int col = nblk + wn*WNT + nt*16 + l16;
            float bv = b0[col];
            #pragma unroll
            for (int r=0;r<4;r++) {
                int row = mblk + wm*WMT + mt*16 + quad*4 + r;
                O[(size_t)row * EMBED + col] = acc[mt][nt][r] + bv;
            }
          }
    } else {
        int which = nblk >> 10;
        const float* bs = (which==0) ? b0 : (which==1) ? b1 : b2;
        if (which < 2) {
            unsigned short* O = (unsigned short*)((which==0) ? o0 : o1);
            float sc = (which==0) ? QSCALE : 1.f;
            #pragma unroll
            for (int mt=0;mt<FM;mt++)
              #pragma unroll
              for (int nt=0;nt<FN;nt++) {
                int coll = (nblk & 1023) + wn*WNT + nt*16 + l16;
                float bv = bs[coll];
                int h = coll >> 6, d = coll & 63;
                #pragma unroll
                for (int r=0;r<4;r++) {
                    int row = mblk + wm*WMT + mt*16 + quad*4 + r;
                    int b = row >> 11, s = row & 2047;
                    O[((size_t)(b*NH + h)*SEQ + s)*HD + d] = f2bf((acc[mt][nt][r] + bv) * sc);
                }
              }
        } else {
            // V: LDS transpose in 2 passes of 128 cols (fits the 64KB buffer);
            // tau-perm applied on the ds_write side; XOR-swizzle sp bits 3-4 by
            // (c&3); readback + fully-coalesced dwordx4 stores.
            unsigned short* T = lds;
            unsigned short* OV = (unsigned short*)o2;
            size_t rowbase = ((size_t)((mblk >> 11)*1024 + (nblk & 1023))) * SEQ + (mblk & 2047);
            __syncthreads();     // all K-loop LDS reads complete before overwrite
            #pragma unroll
            for (int p = 0; p < BN/128; ++p) {
                if ((wn >> 1) == p) {
                    #pragma unroll
                    for (int nt=0;nt<FN;nt++) {
                        int cloc = wn*WNT + nt*16 + l16;       // global col 0..255
                        float bv = bs[(nblk & 1023) + cloc];
                        int sw = (cloc & 3) << 3;
                        #pragma unroll
                        for (int mt=0;mt<FM;mt++) {
                            int row0 = wm*WMT + mt*16 + quad*4;
                            int sp0 = (row0 & ~31) | (((row0 >> 2) & 3) << 3) | (((row0 >> 4) & 1) << 2);
                            ushort4 w;
                            w.x = f2bf(acc[mt][nt][0] + bv);
                            w.y = f2bf(acc[mt][nt][1] + bv);
                            w.z = f2bf(acc[mt][nt][2] + bv);
                            w.w = f2bf(acc[mt][nt][3] + bv);
                            *(ushort4*)(T + (cloc & 127)*256 + (sp0 ^ sw)) = w;
                        }
                    }
                }
                __syncthreads();
                int s0 = (lane & 31) * 8, dloc = lane >> 5;
                #pragma unroll
                for (int i=0;i<128/(NW*2);i++) {
                    int cl = wave*(128/NW) + i*2 + dloc;       // col within pass
                    int sw2 = (cl & 3) << 3;                   // (p*128+cl)&3 == cl&3
                    short8 v = *(const short8*)(T + cl*256 + (s0 ^ sw2));
                    *(short8*)(OV + rowbase + (size_t)(p*128 + cl) * SEQ + s0) = v;
                }
                __syncthreads();
            }
        }
    }
}

// ---- kernel 4: flash attention, double-buffered LDS K/V staging with counted
// vmcnt (stage t+1 issued before computing t; vmcnt(1) leaves next stage in
// flight; raw s_barrier, never vmcnt(0) mid-loop). Register-only P.
// S^T = mfma(A=K, B=Q) -> P^T in regs -> O^T = mfma(A=V^T, B=P^T).
__global__ __launch_bounds__(512, 4) void attn(
    const unsigned short* __restrict__ Q, const unsigned short* __restrict__ K,
    const unsigned short* __restrict__ VTp, unsigned short* __restrict__ O) {
    __shared__ unsigned short kv[2][4096];   // per buf: K tile [0,2048) + V tile [2048,4096)
    unsigned short* kvf = &kv[0][0];
    int tid = threadIdx.x;
    int lane = tid & 63, wave = tid >> 6;   // 8 waves
    int quad = lane >> 4, l16 = lane & 15;
    // 512 blocks: id = bh_low*64 + qblk*8 + xcd
    int id = blockIdx.x;
    int bh = (id & 7) * 8 + (id >> 6);
    int qblk = (id >> 3) & 7;
    int b = bh >> 4, h = bh & 15;
    int q0 = qblk * 256 + wave * 32;
    const unsigned short* Qb = Q + (size_t)bh * SEQ * HD;
    const unsigned short* Kb = K + (size_t)bh * SEQ * HD;
    const unsigned short* Vb = VTp + (size_t)bh * HD * SEQ;
    // staging source (per-lane, swizzled); LDS dest offset per wave
    int li = (wave & 3) * 64 + lane;            // 0..255 chunk index within K or V half
    const unsigned short* src;
    int dstofs = (wave & 3) * 512 + ((wave >> 2) ? 2048 : 0);
    int src_step;
    if (wave < 4) {
        int t = li >> 3, slot = li & 7;
        int dblk = slot ^ (t & 7);
        src = Kb + (size_t)t * HD + dblk * 8;
        src_step = 32 * HD;                      // t advances by 32
    } else {
        int d = li >> 2, slot = li & 3;
        int swz = (d & 3) ^ ((d >> 2) & 3);
        src = Vb + (size_t)d * SEQ + (slot ^ swz) * 8;
        src_step = 32;                           // t advances by 32
    }
    short8 qf[2][2];
    #pragma unroll
    for (int mt=0;mt<2;mt++) {
        const unsigned short* qp = Qb + (size_t)(q0 + mt*16 + l16) * HD + quad*8;
        qf[mt][0] = *(const short8*)(qp);
        qf[mt][1] = *(const short8*)(qp + 32);
    }
    floatx4 o_acc[2][4], l_acc[2];
    #pragma unroll
    for (int mt=0;mt<2;mt++) {
        l_acc[mt] = (floatx4){0.f,0.f,0.f,0.f};
        #pragma unroll
        for (int dt=0;dt<4;dt++) o_acc[mt][dt] = (floatx4){0.f,0.f,0.f,0.f};
    }
    short8 ones;
    #pragma unroll
    for (int jj=0;jj<8;jj++) ones[jj] = (short)0x3F80;   // bf16 1.0
    // precomputed swizzled LDS read offsets (ushort units, relative to buf base)
    int koff[2][2], voff[4];
    #pragma unroll
    for (int nt=0;nt<2;nt++) {
        int t = nt*16 + l16;
        #pragma unroll
        for (int hh=0;hh<2;hh++)
            koff[nt][hh] = t*64 + ((hh*4 + quad) ^ (t & 7)) * 8;
    }
    #pragma unroll
    for (int dt=0;dt<4;dt++) {
        int d = dt*16 + l16;
        voff[dt] = 2048 + d*32 + ((quad ^ (d & 3) ^ ((d >> 2) & 3))) * 8;
    }

    // prologue: stage tile 0 into buf 0
    load_lds16(src, kvf + dstofs);
    src += src_step;

    for (int it = 0; it < 64; ++it) {
        const unsigned short* kb = kvf + (it & 1) * 4096;
        if (it < 63) {
            load_lds16(src, kvf + ((it & 1) ^ 1) * 4096 + dstofs);
            src += src_step;
            asm volatile("s_waitcnt vmcnt(1)" ::: "memory");
        } else {
            asm volatile("s_waitcnt vmcnt(0)" ::: "memory");
        }
        __builtin_amdgcn_s_barrier();
        asm volatile("" ::: "memory");
        short8 kf[2][2], vf[4];
        #pragma unroll
        for (int nt=0;nt<2;nt++) {
            kf[nt][0] = *(const short8*)(kb + koff[nt][0]);
            kf[nt][1] = *(const short8*)(kb + koff[nt][1]);
        }
        #pragma unroll
        for (int dt=0;dt<4;dt++)
            vf[dt] = *(const short8*)(kb + voff[dt]);
        // S^T[t][q]: A = K rows (m = t), B = Q rows (n = q)
        floatx4 sacc[2][2];
        __builtin_amdgcn_s_setprio(1);
        #pragma unroll
        for (int nt=0;nt<2;nt++)
          #pragma unroll
          for (int mt=0;mt<2;mt++) {
            floatx4 s = (floatx4){0.f,0.f,0.f,0.f};
            s = __builtin_amdgcn_mfma_f32_16x16x32_bf16(kf[nt][0], qf[mt][0], s, 0, 0, 0);
            s = __builtin_amdgcn_mfma_f32_16x16x32_bf16(kf[nt][1], qf[mt][1], s, 0, 0, 0);
            sacc[nt][mt] = s;
          }
        __builtin_amdgcn_s_setprio(0);
        // P^T fragment in registers: slot j = nt*4 + r (matched by VT tau-perm)
        short8 pf[2];
        #pragma unroll
        for (int mt=0;mt<2;mt++) {
            uintx4 pu;
            #pragma unroll
            for (int jp=0;jp<4;jp++) {
                int nt = jp >> 1, rp = (jp & 1) * 2;
                union { float f; unsigned int u; } e0, e1;
                e0.f = __builtin_amdgcn_exp2f(sacc[nt][mt][rp]);
                e1.f = __builtin_amdgcn_exp2f(sacc[nt][mt][rp+1]);
                pu[jp] = ((e1.u + 0x8000u) & 0xFFFF0000u) | ((e0.u + 0x8000u) >> 16);
            }
            pf[mt] = __builtin_bit_cast(short8, pu);
        }
        __builtin_amdgcn_s_setprio(1);
        #pragma unroll
        for (int mt=0;mt<2;mt++) {
            l_acc[mt] = __builtin_amdgcn_mfma_f32_16x16x32_bf16(ones, pf[mt], l_acc[mt], 0, 0, 0);
            #pragma unroll
            for (int dt=0;dt<4;dt++)
                o_acc[mt][dt] = __builtin_amdgcn_mfma_f32_16x16x32_bf16(vf[dt], pf[mt], o_acc[mt][dt], 0, 0, 0);
        }
        __builtin_amdgcn_s_setprio(0);
        asm volatile("" ::: "memory");
        __builtin_amdgcn_s_barrier();   // all reads of this buf done before next overwrite
    }
    // epilogue: o_acc[mt][dt][r] = O^T[d = dt*16+quad*4+r][q = mt*16+l16]; l replicated
    #pragma unroll
    for (int mt=0;mt<2;mt++) {
        float inv = 1.f / l_acc[mt][0];
        int s = q0 + mt*16 + l16;
        #pragma unroll
        for (int dt=0;dt<4;dt++) {
            ushort4 w;
            w.x = f2bf(o_acc[mt][dt][0]*inv);
            w.y = f2bf(o_acc[mt][dt][1]*inv);
            w.z = f2bf(o_acc[mt][dt][2]*inv);
            w.w = f2bf(o_acc[mt][dt][3]*inv);
            *(ushort4*)(O + ((size_t)b*SEQ + s)*EMBED + h*HD + dt*16 + quad*4) = w;
        }
    }
}

extern "C" void kernel_launch(void* const* d_in, const int* in_sizes, int n_in,
                              void* d_out, int out_size, void* d_ws, size_t ws_size,
                              hipStream_t stream) {
    const float* x  = (const float*)d_in[0];
    const float* Wq = (const float*)d_in[1]; const float* bq = (const float*)d_in[2];
    const float* Wk = (const float*)d_in[3]; const float* bk = (const float*)d_in[4];
    const float* Wv = (const float*)d_in[5]; const float* bv = (const float*)d_in[6];
    const float* Wo = (const float*)d_in[7]; const float* bo = (const float*)d_in[8];
    char* ws = (char*)d_ws;
    unsigned short* xb  = (unsigned short*)(ws);                      // 16 MB, reused as O later
    unsigned short* WqT = (unsigned short*)(ws + (16ull<<20));        // 2 MB each; Wq|Wk|Wv contiguous
    unsigned short* WkT = (unsigned short*)(ws + (18ull<<20));
    unsigned short* WvT = (unsigned short*)(ws + (20ull<<20));
    unsigned short* WoT = (unsigned short*)(ws + (22ull<<20));
    unsigned short* Qb  = (unsigned short*)(ws + (24ull<<20));        // 16 MB
    unsigned short* Kb  = (unsigned short*)(ws + (40ull<<20));        // 16 MB
    unsigned short* VTb = (unsigned short*)(ws + (56ull<<20));        // 16 MB  (total 72 MB)
    unsigned short* Ob  = xb;   // xb dead after QKV GEMM; reuse for attention output

    cvt_x<<<(M_TOT*EMBED)/1024, 256, 0, stream>>>(x, xb);
    wtrans<<<dim3(32,32,4), dim3(32,8), 0, stream>>>(Wq,Wk,Wv,Wo, WqT,WkT,WvT,WoT);
    // fused QKV: BT = WqT|WkT|WvT (contiguous), N = 3072 -> 32x12 = 384 blocks,
    // 64KB LDS -> 2 blocks/CU co-resident
    gemmk<0,256,256,8><<<dim3(384), 512, 0, stream>>>(xb, WqT, bq, bk, bv, Qb, Kb, VTb);
    attn<<<dim3(512), 512, 0, stream>>>(Qb, Kb, VTb, Ob);
    // out-proj: 128^2 tiles -> 64x8 = 512 blocks, 32KB LDS -> 4 blocks/CU
    gemmk<1,128,128,4><<<dim3(512), 256, 0, stream>>>(Ob, WoT, bo, bo, bo, (float*)d_out, nullptr, nullptr);
}

// Round 6
// 260.419 us; speedup vs baseline: 2.5825x; 2.5825x over previous
//
#include <hip/hip_runtime.h>
#include <stdint.h>

#define EMBED 1024
#define NH 16
#define HD 64
#define SEQ 2048
#define BATCH 4
#define M_TOT (BATCH*SEQ)   // 8192
#define QSCALE 0.18033688011112042f   // log2(e)/sqrt(HD)

typedef __attribute__((ext_vector_type(8))) short short8;
typedef __attribute__((ext_vector_type(4))) float floatx4;
typedef __attribute__((ext_vector_type(4))) unsigned int uintx4;

__device__ __forceinline__ unsigned short f2bf(float f) {
    union { float f; unsigned int u; } v; v.f = f;
    unsigned int r = v.u + 0x7fffu + ((v.u >> 16) & 1u);
    return (unsigned short)(r >> 16);
}

__device__ __forceinline__ void load_lds16(const unsigned short* g, unsigned short* l) {
    __builtin_amdgcn_global_load_lds(
        (const __attribute__((address_space(1))) unsigned int*)g,
        (__attribute__((address_space(3))) unsigned int*)l, 16, 0, 0);
}

// ---- kernel 1: x fp32 -> bf16 ----
__global__ void cvt_x(const float* __restrict__ x, unsigned short* __restrict__ xb) {
    int i = (blockIdx.x * 256 + threadIdx.x) * 4;
    float4 v = *(const float4*)(x + i);
    ushort4 o;
    o.x = f2bf(v.x); o.y = f2bf(v.y); o.z = f2bf(v.z); o.w = f2bf(v.w);
    *(ushort4*)(xb + i) = o;
}

// ---- kernel 2: transpose W [k][n] fp32 -> WT [n][k] bf16 ----
__global__ void wtrans(const float* __restrict__ w0, const float* __restrict__ w1,
                       const float* __restrict__ w2, const float* __restrict__ w3,
                       unsigned short* __restrict__ t0, unsigned short* __restrict__ t1,
                       unsigned short* __restrict__ t2, unsigned short* __restrict__ t3) {
    __shared__ float tile[32][33];
    const float* W; unsigned short* T;
    switch (blockIdx.z) { case 0: W=w0; T=t0; break; case 1: W=w1; T=t1; break;
                          case 2: W=w2; T=t2; break; default: W=w3; T=t3; }
    int n0 = blockIdx.x * 32, k0 = blockIdx.y * 32;
    int tx = threadIdx.x, ty = threadIdx.y;
    #pragma unroll
    for (int i = 0; i < 4; i++)
        tile[ty + i*8][tx] = W[(k0 + ty + i*8) * EMBED + n0 + tx];
    __syncthreads();
    #pragma unroll
    for (int i = 0; i < 4; i++)
        T[(n0 + ty + i*8) * EMBED + k0 + tx] = f2bf(tile[tx][ty + i*8]);
}

// ---- kernel 3: 128x128 GEMM, BK=32, double-buffered, REGISTER-FEASIBLE HIGH
// OCCUPANCY (round-5 lesson: occupancy cap and acc size must be co-designed;
// acc[8][4]=128 AGPR under a 128-reg cap spilled 2GB to scratch).
// Config: 512 thr = 8 waves (2m x 4n), wave tile 64x32, acc[4][2] = 32 AGPR,
// ~70 arch VGPR -> ~105 unified < 128 cap => launch_bounds(512,4) gives
// 2 blocks/CU (16 waves/CU, 4/SIMD) with LDS 32KB double-buffer (34KB with
// V-transpose scratch). Two desynced blocks/CU absorb barrier straggle that
// capped rounds 0-4 (~4000cy/K-tile with all pipes <25%).
// C[M,N] = A[M,K] @ BT[N,K]^T + bias, K=1024 (32 K-tiles).
// LDS swizzle (BK=32: row = 64B = 4 chunks of 16B): slot s of row r holds
// logical chunk s^(r&3); inverse-swizzled global source (global_load_lds dest
// is linear), same XOR on ds_read. Wave frag read = 16 full 64B rows -> 0 conflicts
// (round-4 measured 0 with this exact pattern).
// Per tile t: {6 ds_read_b128; stage t+1 -> buf^1 (2 gloads); 8 MFMA; vmcnt(0);
// s_barrier}. Safety: stage(t+1) overwrites buf(t-1), whose reads completed
// before barrier(t-1) (each wave's reads complete before its own MFMA(t-1)).
// Grids quantize exactly: QKV 64x24=1536 = 3 full passes at 2/CU; proj
// 64x8=512 = 1 full pass (round-4 proj ran 128 blocks at 1/CU: ~55us tail).
// MODE 0: fused QKV (N=3072), which = nblk>>10: 0 -> Qb bf16 [B,H,S,D]*QSCALE;
//   1 -> Kb; 2 -> VTp bf16 [B,H,D,SEQ] tau-perm via padded LDS transpose.
// MODE 1: out-proj fp32 [M,1024] + b0 -> o0.
template<int MODE>
__global__ __launch_bounds__(512, 4) void gemmk(
        const unsigned short* __restrict__ A, const unsigned short* __restrict__ BT,
        const float* __restrict__ b0, const float* __restrict__ b1, const float* __restrict__ b2,
        void* __restrict__ o0, void* __restrict__ o1, void* __restrict__ o2) {
    constexpr int BM = 128, BN = 128;
    constexpr int BUFS = (BM+BN)*32;           // 8192 ushorts = 16KB per buffer
    __shared__ unsigned short lds[128*136];    // 34KB; K-loop uses [0, 2*BUFS)
    const int tid = threadIdx.x;
    const int lane = tid & 63, wave = tid >> 6;
    const int quad = lane >> 4, l16 = lane & 15;
    const int wm = wave >> 2, wn = wave & 3;   // wave tile 64x32 at (wm*64, wn*32)
    const int id = blockIdx.x;
    constexpr int MS = (M_TOT/BM)/8;           // 8 m-blocks per XCD stripe
    const int xcd = id & 7, j = id >> 3;
    const int mblk = (xcd * MS + (j % MS)) * BM;
    const int nblk = (j / MS) * BN;

    // staging: thread tid = (row tid>>2, slot tid&3); slot s loads logical chunk
    // s^(row&3) (inverse-swizzled source). One issue covers all 128 rows/operand.
    const int srow = tid >> 2;
    const int scol = ((tid & 3) ^ (srow & 3)) * 8;
    const unsigned short* Asrc = A  + (size_t)(mblk + srow) * EMBED + scol;
    const unsigned short* Bsrc = BT + (size_t)(nblk + srow) * EMBED + scol;
    unsigned short* sda = lds + wave * 512;            // wave stages rows w*16..+15
    unsigned short* sdb = lds + BM*32 + wave * 512;

    // swizzled fragment-read base: row ..+l16, logical chunk quad at slot quad^(l16&3)
    const int cs = (quad ^ (l16 & 3)) * 8;
    const unsigned short* Abase = lds + (wm*64 + l16)*32 + cs;
    const unsigned short* Bbase = lds + BM*32 + (wn*32 + l16)*32 + cs;

    floatx4 acc[4][2];
    #pragma unroll
    for (int m=0;m<4;m++)
      #pragma unroll
      for (int n=0;n<2;n++) acc[m][n] = (floatx4){0.f,0.f,0.f,0.f};

#define ST(t_) do { \
    const int buf_ = (t_) & 1; const int ko_ = (t_)*32; \
    load_lds16(Asrc + ko_, sda + buf_*BUFS); \
    load_lds16(Bsrc + ko_, sdb + buf_*BUFS); \
  } while(0)

    ST(0);
    asm volatile("s_waitcnt vmcnt(0)" ::: "memory");
    asm volatile("s_barrier" ::: "memory");

    #pragma unroll 2
    for (int t = 0; t < 32; ++t) {
        const int bo = (t & 1) * BUFS;
        short8 fA[4], fB[2];
        #pragma unroll
        for (int m=0;m<4;m++) fA[m] = *(const short8*)(Abase + bo + m*512);
        #pragma unroll
        for (int n=0;n<2;n++) fB[n] = *(const short8*)(Bbase + bo + n*512);
        if (t < 31) ST(t+1);
        #pragma unroll
        for (int m=0;m<4;m++)
          #pragma unroll
          for (int n=0;n<2;n++)
            acc[m][n] = __builtin_amdgcn_mfma_f32_16x16x32_bf16(fA[m], fB[n], acc[m][n], 0,0,0);
        if (t < 31) {
            asm volatile("s_waitcnt vmcnt(0)" ::: "memory");
            asm volatile("s_barrier" ::: "memory");
        }
    }
#undef ST

    // epilogue: C/D layout col=lane&15, row=quad*4+reg
    if constexpr (MODE == 1) {
        float* O = (float*)o0;
        #pragma unroll
        for (int mt=0;mt<4;mt++)
          #pragma unroll
          for (int nt=0;nt<2;nt++) {
            int col = nblk + wn*32 + nt*16 + l16;
            float bv = b0[col];
            #pragma unroll
            for (int r=0;r<4;r++) {
                int row = mblk + wm*64 + mt*16 + quad*4 + r;
                O[(size_t)row * EMBED + col] = acc[mt][nt][r] + bv;
            }
          }
    } else {
        int which = nblk >> 10;
        const float* bs = (which==0) ? b0 : (which==1) ? b1 : b2;
        if (which < 2) {
            unsigned short* O = (unsigned short*)((which==0) ? o0 : o1);
            float sc = (which==0) ? QSCALE : 1.f;
            #pragma unroll
            for (int mt=0;mt<4;mt++)
              #pragma unroll
              for (int nt=0;nt<2;nt++) {
                int coll = (nblk & 1023) + wn*32 + nt*16 + l16;
                float bv = bs[coll];
                int h = coll >> 6, d = coll & 63;
                #pragma unroll
                for (int r=0;r<4;r++) {
                    int row = mblk + wm*64 + mt*16 + quad*4 + r;
                    int b = row >> 11, s = row & 2047;
                    O[((size_t)(b*NH + h)*SEQ + s)*HD + d] = f2bf((acc[mt][nt][r] + bv) * sc);
                }
              }
        } else {
            // V: padded LDS transpose (T[c][sp], stride 136 ushorts = 272B, a
            // multiple of 16B so ds_read_b128 stays aligned; 272B = 68 banks
            // rotates banks by 4 per row). tau-perm applied on the write side:
            // within each 32-row block, position p = ((s>>2)&3)*8+((s>>4)&1)*4+(s&3).
            // Readback: fully-coalesced 16B/lane stores (256B per column segment).
            unsigned short* T = lds;
            unsigned short* OV = (unsigned short*)o2;
            size_t rowbase = ((size_t)((mblk >> 11)*1024 + (nblk & 1023))) * SEQ + (mblk & 2047);
            __syncthreads();     // all K-loop LDS reads complete before overwrite
            #pragma unroll
            for (int nt=0;nt<2;nt++) {
                int cloc = wn*32 + nt*16 + l16;            // local col 0..127
                float bv = bs[(nblk & 1023) + cloc];
                #pragma unroll
                for (int mt=0;mt<4;mt++) {
                    int row0 = wm*64 + mt*16 + quad*4;     // local row 0..124, mult of 4
                    int sp0 = (row0 & ~31) | (((row0 >> 2) & 3) << 3) | (((row0 >> 4) & 1) << 2);
                    ushort4 w;
                    w.x = f2bf(acc[mt][nt][0] + bv);
                    w.y = f2bf(acc[mt][nt][1] + bv);
                    w.z = f2bf(acc[mt][nt][2] + bv);
                    w.w = f2bf(acc[mt][nt][3] + bv);
                    *(ushort4*)(T + cloc*136 + sp0) = w;
                }
            }
            __syncthreads();
            int s0 = (lane & 15) * 8, dloc = lane >> 4;    // 16 s-chunks x 4 cols
            #pragma unroll
            for (int i=0;i<4;i++) {
                int c = wave*16 + i*4 + dloc;              // local col 0..127
                short8 v = *(const short8*)(T + c*136 + s0);
                *(short8*)(OV + rowbase + (size_t)c * SEQ + s0) = v;
            }
        }
    }
}

// ---- kernel 4: flash attention, double-buffered LDS K/V staging with counted
// vmcnt (stage t+1 issued before computing t; vmcnt(1) leaves next stage in
// flight; raw s_barrier, never vmcnt(0) mid-loop). Register-only P; P->bf16
// pack via v_cvt_pk_bf16_f32 (replaces 5-op manual rounding per pair; RNE).
// S^T = mfma(A=K, B=Q) -> P^T in regs -> O^T = mfma(A=V^T, B=P^T).
__global__ __launch_bounds__(512, 4) void attn(
    const unsigned short* __restrict__ Q, const unsigned short* __restrict__ K,
    const unsigned short* __restrict__ VTp, unsigned short* __restrict__ O) {
    __shared__ unsigned short kv[2][4096];   // per buf: K tile [0,2048) + V tile [2048,4096)
    unsigned short* kvf = &kv[0][0];
    int tid = threadIdx.x;
    int lane = tid & 63, wave = tid >> 6;   // 8 waves
    int quad = lane >> 4, l16 = lane & 15;
    // 512 blocks: id = bh_low*64 + qblk*8 + xcd
    int id = blockIdx.x;
    int bh = (id & 7) * 8 + (id >> 6);
    int qblk = (id >> 3) & 7;
    int b = bh >> 4, h = bh & 15;
    int q0 = qblk * 256 + wave * 32;
    const unsigned short* Qb = Q + (size_t)bh * SEQ * HD;
    const unsigned short* Kb = K + (size_t)bh * SEQ * HD;
    const unsigned short* Vb = VTp + (size_t)bh * HD * SEQ;
    // staging source (per-lane, swizzled); LDS dest offset per wave
    int li = (wave & 3) * 64 + lane;            // 0..255 chunk index within K or V half
    const unsigned short* src;
    int dstofs = (wave & 3) * 512 + ((wave >> 2) ? 2048 : 0);
    int src_step;
    if (wave < 4) {
        int t = li >> 3, slot = li & 7;
        int dblk = slot ^ (t & 7);
        src = Kb + (size_t)t * HD + dblk * 8;
        src_step = 32 * HD;                      // t advances by 32
    } else {
        int d = li >> 2, slot = li & 3;
        int swz = (d & 3) ^ ((d >> 2) & 3);
        src = Vb + (size_t)d * SEQ + (slot ^ swz) * 8;
        src_step = 32;                           // t advances by 32
    }
    short8 qf[2][2];
    #pragma unroll
    for (int mt=0;mt<2;mt++) {
        const unsigned short* qp = Qb + (size_t)(q0 + mt*16 + l16) * HD + quad*8;
        qf[mt][0] = *(const short8*)(qp);
        qf[mt][1] = *(const short8*)(qp + 32);
    }
    floatx4 o_acc[2][4], l_acc[2];
    #pragma unroll
    for (int mt=0;mt<2;mt++) {
        l_acc[mt] = (floatx4){0.f,0.f,0.f,0.f};
        #pragma unroll
        for (int dt=0;dt<4;dt++) o_acc[mt][dt] = (floatx4){0.f,0.f,0.f,0.f};
    }
    short8 ones;
    #pragma unroll
    for (int jj=0;jj<8;jj++) ones[jj] = (short)0x3F80;   // bf16 1.0
    // precomputed swizzled LDS read offsets (ushort units, relative to buf base)
    int koff[2][2], voff[4];
    #pragma unroll
    for (int nt=0;nt<2;nt++) {
        int t = nt*16 + l16;
        #pragma unroll
        for (int hh=0;hh<2;hh++)
            koff[nt][hh] = t*64 + ((hh*4 + quad) ^ (t & 7)) * 8;
    }
    #pragma unroll
    for (int dt=0;dt<4;dt++) {
        int d = dt*16 + l16;
        voff[dt] = 2048 + d*32 + ((quad ^ (d & 3) ^ ((d >> 2) & 3))) * 8;
    }

    // prologue: stage tile 0 into buf 0
    load_lds16(src, kvf + dstofs);
    src += src_step;

    for (int it = 0; it < 64; ++it) {
        const unsigned short* kb = kvf + (it & 1) * 4096;
        if (it < 63) {
            load_lds16(src, kvf + ((it & 1) ^ 1) * 4096 + dstofs);
            src += src_step;
            asm volatile("s_waitcnt vmcnt(1)" ::: "memory");
        } else {
            asm volatile("s_waitcnt vmcnt(0)" ::: "memory");
        }
        __builtin_amdgcn_s_barrier();
        asm volatile("" ::: "memory");
        short8 kf[2][2], vf[4];
        #pragma unroll
        for (int nt=0;nt<2;nt++) {
            kf[nt][0] = *(const short8*)(kb + koff[nt][0]);
            kf[nt][1] = *(const short8*)(kb + koff[nt][1]);
        }
        #pragma unroll
        for (int dt=0;dt<4;dt++)
            vf[dt] = *(const short8*)(kb + voff[dt]);
        // S^T[t][q]: A = K rows (m = t), B = Q rows (n = q)
        floatx4 sacc[2][2];
        __builtin_amdgcn_s_setprio(1);
        #pragma unroll
        for (int nt=0;nt<2;nt++)
          #pragma unroll
          for (int mt=0;mt<2;mt++) {
            floatx4 s = (floatx4){0.f,0.f,0.f,0.f};
            s = __builtin_amdgcn_mfma_f32_16x16x32_bf16(kf[nt][0], qf[mt][0], s, 0, 0, 0);
            s = __builtin_amdgcn_mfma_f32_16x16x32_bf16(kf[nt][1], qf[mt][1], s, 0, 0, 0);
            sacc[nt][mt] = s;
          }
        __builtin_amdgcn_s_setprio(0);
        // P^T fragment in registers: slot j = nt*4 + r (matched by VT tau-perm);
        // pack two exp2 results per dword with v_cvt_pk_bf16_f32 (lo=src0, hi=src1)
        short8 pf[2];
        #pragma unroll
        for (int mt=0;mt<2;mt++) {
            uintx4 pu;
            #pragma unroll
            for (int jp=0;jp<4;jp++) {
                int nt = jp >> 1, rp = (jp & 1) * 2;
                float e0 = __builtin_amdgcn_exp2f(sacc[nt][mt][rp]);
                float e1 = __builtin_amdgcn_exp2f(sacc[nt][mt][rp+1]);
                unsigned int w;
                asm("v_cvt_pk_bf16_f32 %0, %1, %2" : "=v"(w) : "v"(e0), "v"(e1));
                pu[jp] = w;
            }
            pf[mt] = __builtin_bit_cast(short8, pu);
        }
        __builtin_amdgcn_s_setprio(1);
        #pragma unroll
        for (int mt=0;mt<2;mt++) {
            l_acc[mt] = __builtin_amdgcn_mfma_f32_16x16x32_bf16(ones, pf[mt], l_acc[mt], 0, 0, 0);
            #pragma unroll
            for (int dt=0;dt<4;dt++)
                o_acc[mt][dt] = __builtin_amdgcn_mfma_f32_16x16x32_bf16(vf[dt], pf[mt], o_acc[mt][dt], 0, 0, 0);
        }
        __builtin_amdgcn_s_setprio(0);
        asm volatile("" ::: "memory");
        __builtin_amdgcn_s_barrier();   // all reads of this buf done before next overwrite
    }
    // epilogue: o_acc[mt][dt][r] = O^T[d = dt*16+quad*4+r][q = mt*16+l16]; l replicated
    #pragma unroll
    for (int mt=0;mt<2;mt++) {
        float inv = 1.f / l_acc[mt][0];
        int s = q0 + mt*16 + l16;
        #pragma unroll
        for (int dt=0;dt<4;dt++) {
            ushort4 w;
            w.x = f2bf(o_acc[mt][dt][0]*inv);
            w.y = f2bf(o_acc[mt][dt][1]*inv);
            w.z = f2bf(o_acc[mt][dt][2]*inv);
            w.w = f2bf(o_acc[mt][dt][3]*inv);
            *(ushort4*)(O + ((size_t)b*SEQ + s)*EMBED + h*HD + dt*16 + quad*4) = w;
        }
    }
}

extern "C" void kernel_launch(void* const* d_in, const int* in_sizes, int n_in,
                              void* d_out, int out_size, void* d_ws, size_t ws_size,
                              hipStream_t stream) {
    const float* x  = (const float*)d_in[0];
    const float* Wq = (const float*)d_in[1]; const float* bq = (const float*)d_in[2];
    const float* Wk = (const float*)d_in[3]; const float* bk = (const float*)d_in[4];
    const float* Wv = (const float*)d_in[5]; const float* bv = (const float*)d_in[6];
    const float* Wo = (const float*)d_in[7]; const float* bo = (const float*)d_in[8];
    char* ws = (char*)d_ws;
    unsigned short* xb  = (unsigned short*)(ws);                      // 16 MB, reused as O later
    unsigned short* WqT = (unsigned short*)(ws + (16ull<<20));        // 2 MB each; Wq|Wk|Wv contiguous
    unsigned short* WkT = (unsigned short*)(ws + (18ull<<20));
    unsigned short* WvT = (unsigned short*)(ws + (20ull<<20));
    unsigned short* WoT = (unsigned short*)(ws + (22ull<<20));
    unsigned short* Qb  = (unsigned short*)(ws + (24ull<<20));        // 16 MB
    unsigned short* Kb  = (unsigned short*)(ws + (40ull<<20));        // 16 MB
    unsigned short* VTb = (unsigned short*)(ws + (56ull<<20));        // 16 MB  (total 72 MB)
    unsigned short* Ob  = xb;   // xb dead after QKV GEMM; reuse for attention output

    cvt_x<<<(M_TOT*EMBED)/1024, 256, 0, stream>>>(x, xb);
    wtrans<<<dim3(32,32,4), dim3(32,8), 0, stream>>>(Wq,Wk,Wv,Wo, WqT,WkT,WvT,WoT);
    // fused QKV: BT = WqT|WkT|WvT (contiguous), N = 3072 -> 64x24 = 1536 blocks,
    // 2 blocks/CU -> exactly 3 full passes
    gemmk<0><<<dim3(1536), 512, 0, stream>>>(xb, WqT, bq, bk, bv, Qb, Kb, VTb);
    attn<<<dim3(512), 512, 0, stream>>>(Qb, Kb, VTb, Ob);
    // out-proj: 64x8 = 512 blocks, 2 blocks/CU -> exactly 1 full pass
    gemmk<1><<<dim3(512), 512, 0, stream>>>(Ob, WoT, bo, bo, bo, (float*)d_out, nullptr, nullptr);
}

// Round 7
// 248.622 us; speedup vs baseline: 2.7051x; 1.0474x over previous
//
#include <hip/hip_runtime.h>
#include <stdint.h>

#define EMBED 1024
#define NH 16
#define HD 64
#define SEQ 2048
#define BATCH 4
#define M_TOT (BATCH*SEQ)   // 8192
#define QSCALE 0.18033688011112042f   // log2(e)/sqrt(HD)

typedef __attribute__((ext_vector_type(8))) short short8;
typedef __attribute__((ext_vector_type(4))) float floatx4;
typedef __attribute__((ext_vector_type(4))) unsigned int uintx4;

__device__ __forceinline__ unsigned short f2bf(float f) {
    union { float f; unsigned int u; } v; v.f = f;
    unsigned int r = v.u + 0x7fffu + ((v.u >> 16) & 1u);
    return (unsigned short)(r >> 16);
}

__device__ __forceinline__ void load_lds16(const unsigned short* g, unsigned short* l) {
    __builtin_amdgcn_global_load_lds(
        (const __attribute__((address_space(1))) unsigned int*)g,
        (__attribute__((address_space(3))) unsigned int*)l, 16, 0, 0);
}

// ---- kernel 1: x fp32 -> bf16 ----
__global__ void cvt_x(const float* __restrict__ x, unsigned short* __restrict__ xb) {
    int i = (blockIdx.x * 256 + threadIdx.x) * 4;
    float4 v = *(const float4*)(x + i);
    ushort4 o;
    o.x = f2bf(v.x); o.y = f2bf(v.y); o.z = f2bf(v.z); o.w = f2bf(v.w);
    *(ushort4*)(xb + i) = o;
}

// ---- kernel 2: transpose W [k][n] fp32 -> WT [n][k] bf16 ----
__global__ void wtrans(const float* __restrict__ w0, const float* __restrict__ w1,
                       const float* __restrict__ w2, const float* __restrict__ w3,
                       unsigned short* __restrict__ t0, unsigned short* __restrict__ t1,
                       unsigned short* __restrict__ t2, unsigned short* __restrict__ t3) {
    __shared__ float tile[32][33];
    const float* W; unsigned short* T;
    switch (blockIdx.z) { case 0: W=w0; T=t0; break; case 1: W=w1; T=t1; break;
                          case 2: W=w2; T=t2; break; default: W=w3; T=t3; }
    int n0 = blockIdx.x * 32, k0 = blockIdx.y * 32;
    int tx = threadIdx.x, ty = threadIdx.y;
    #pragma unroll
    for (int i = 0; i < 4; i++)
        tile[ty + i*8][tx] = W[(k0 + ty + i*8) * EMBED + n0 + tx];
    __syncthreads();
    #pragma unroll
    for (int i = 0; i < 4; i++)
        T[(n0 + ty + i*8) * EMBED + k0 + tx] = f2bf(tile[tx][ty + i*8]);
}

// ---- kernel 3: 128x128 GEMM, BK=32, 4-buffer deep pipeline, conflict-free swizzle.
// Round-6 postmortem: (a) SQ_LDS_BANK_CONFLICT=9.5M -- 64B rows repeat banks every
// 2 rows but the r&3 XOR repeats every 4, so lanes l16={0,4,8,12} hit the same
// 4-bank slot (4-way). Fix: f(r)=(r&3)^((r>>2)&3), period 16; per 8-lane issue
// group the 8 slots cover all 32 banks exactly once (audited). (b) per-tile
// vmcnt(0) drain exposed ~900cy HBM misses (A-stripe+B panel = 8MB > 4MB L2/XCD).
// Fix: 4 LDS buffers (64KB, still 2 blocks/CU), stage distance 3, ONE vmcnt(4)
// + barrier per tile; never drains to 0 until the 3-tile tail.
//   WAR: ST(t+3) targets buf((t-1)&3); its reads retired before barrier(t-1),
//        and ST issues after that barrier.
//   Ready: vmcnt(4) at end of t-1 (outstanding ST(t),ST(t+1),ST(t+2)=6) completes
//          exactly ST(t); barrier makes it block-wide.
// Config: 512 thr = 8 waves (2m x 4n), wave tile 64x32, acc[4][2]=32 AGPR,
// VGPR_Count=40 (round 6) -> far under the launch_bounds(512,4) 128-reg cap.
// Grids quantize exactly: QKV 64x24=1536 = 3 passes at 2/CU; proj 64x8=512 = 1 pass.
// MODE 0: fused QKV (N=3072), which=nblk>>10: 0->Qb bf16 [B,H,S,D]*QSCALE; 1->Kb;
//   2->VTp bf16 [B,H,D,SEQ] tau-perm via padded LDS transpose.
// MODE 1: out-proj fp32 [M,1024] + b0 -> o0.
#define GBUFS 8192   // ushorts per K-tile buffer (16KB: A 128x32 | B 128x32)

template<bool STG, int WAITN>
__device__ __forceinline__ void ktile(int t,
        const unsigned short* Abase, const unsigned short* Bbase,
        const unsigned short* Asrc, const unsigned short* Bsrc,
        unsigned short* sda, unsigned short* sdb, floatx4 (&acc)[4][2]) {
    const int bo = (t & 3) * GBUFS;
    short8 fA[4], fB[2];
    #pragma unroll
    for (int m=0;m<4;m++) fA[m] = *(const short8*)(Abase + bo + m*512);
    #pragma unroll
    for (int n=0;n<2;n++) fB[n] = *(const short8*)(Bbase + bo + n*512);
    if (STG) {
        const int buf_ = (t+3) & 3; const int ko_ = (t+3)*32;
        load_lds16(Asrc + ko_, sda + buf_*GBUFS);
        load_lds16(Bsrc + ko_, sdb + buf_*GBUFS);
    }
    #pragma unroll
    for (int m=0;m<4;m++)
      #pragma unroll
      for (int n=0;n<2;n++)
        acc[m][n] = __builtin_amdgcn_mfma_f32_16x16x32_bf16(fA[m], fB[n], acc[m][n], 0,0,0);
    if (WAITN == 4)      { asm volatile("s_waitcnt vmcnt(4)" ::: "memory"); asm volatile("s_barrier" ::: "memory"); }
    else if (WAITN == 2) { asm volatile("s_waitcnt vmcnt(2)" ::: "memory"); asm volatile("s_barrier" ::: "memory"); }
    else if (WAITN == 0) { asm volatile("s_waitcnt vmcnt(0)" ::: "memory"); asm volatile("s_barrier" ::: "memory"); }
}

template<int MODE>
__global__ __launch_bounds__(512, 4) void gemmk(
        const unsigned short* __restrict__ A, const unsigned short* __restrict__ BT,
        const float* __restrict__ b0, const float* __restrict__ b1, const float* __restrict__ b2,
        void* __restrict__ o0, void* __restrict__ o1, void* __restrict__ o2) {
    constexpr int BM = 128, BN = 128;
    __shared__ unsigned short lds[4*GBUFS];    // 64KB: 4 bufs x [A 4KB | B 4KB... x2]
    const int tid = threadIdx.x;
    const int lane = tid & 63, wave = tid >> 6;
    const int quad = lane >> 4, l16 = lane & 15;
    const int wm = wave >> 2, wn = wave & 3;   // wave tile 64x32 at (wm*64, wn*32)
    const int id = blockIdx.x;
    constexpr int MS = (M_TOT/BM)/8;           // 8 m-blocks per XCD stripe
    const int xcd = id & 7, j = id >> 3;
    const int mblk = (xcd * MS + (j % MS)) * BM;
    const int nblk = (j / MS) * BN;

    // staging: thread tid = (row tid>>2, slot tid&3); slot s holds logical chunk
    // s ^ f(row), f(r) = (r&3)^((r>>2)&3)  (inverse-swizzled global source).
    const int srow = tid >> 2;
    const int scol = ((tid & 3) ^ (srow & 3) ^ ((srow >> 2) & 3)) * 8;
    const unsigned short* Asrc = A  + (size_t)(mblk + srow) * EMBED + scol;
    const unsigned short* Bsrc = BT + (size_t)(nblk + srow) * EMBED + scol;
    unsigned short* sda = lds + wave * 512;            // wave stages rows w*16..+15
    unsigned short* sdb = lds + BM*32 + wave * 512;

    // swizzled fragment read: row ..+l16 (16|base so f's row part = f(l16)),
    // logical chunk quad at slot quad ^ f(l16)
    const int cs = (quad ^ (l16 & 3) ^ ((l16 >> 2) & 3)) * 8;
    const unsigned short* Abase = lds + (wm*64 + l16)*32 + cs;
    const unsigned short* Bbase = lds + BM*32 + (wn*32 + l16)*32 + cs;

    floatx4 acc[4][2];
    #pragma unroll
    for (int m=0;m<4;m++)
      #pragma unroll
      for (int n=0;n<2;n++) acc[m][n] = (floatx4){0.f,0.f,0.f,0.f};

    // prologue: stage tiles 0,1,2 (in order); vmcnt(4) completes tile 0 only
    #pragma unroll
    for (int p=0;p<3;p++) {
        load_lds16(Asrc + p*32, sda + p*GBUFS);
        load_lds16(Bsrc + p*32, sdb + p*GBUFS);
    }
    asm volatile("s_waitcnt vmcnt(4)" ::: "memory");
    asm volatile("s_barrier" ::: "memory");

    #pragma unroll 4
    for (int t = 0; t < 28; ++t)
        ktile<true,4>(t, Abase, Bbase, Asrc, Bsrc, sda, sdb, acc);
    ktile<true, 4>(28, Abase, Bbase, Asrc, Bsrc, sda, sdb, acc);  // stages ST(31)
    ktile<false,2>(29, Abase, Bbase, Asrc, Bsrc, sda, sdb, acc);
    ktile<false,0>(30, Abase, Bbase, Asrc, Bsrc, sda, sdb, acc);
    ktile<false,-1>(31, Abase, Bbase, Asrc, Bsrc, sda, sdb, acc);

    // epilogue: C/D layout col=lane&15, row=quad*4+reg
    if constexpr (MODE == 1) {
        float* O = (float*)o0;
        #pragma unroll
        for (int mt=0;mt<4;mt++)
          #pragma unroll
          for (int nt=0;nt<2;nt++) {
            int col = nblk + wn*32 + nt*16 + l16;
            float bv = b0[col];
            #pragma unroll
            for (int r=0;r<4;r++) {
                int row = mblk + wm*64 + mt*16 + quad*4 + r;
                O[(size_t)row * EMBED + col] = acc[mt][nt][r] + bv;
            }
          }
    } else {
        int which = nblk >> 10;
        const float* bs = (which==0) ? b0 : (which==1) ? b1 : b2;
        if (which < 2) {
            unsigned short* O = (unsigned short*)((which==0) ? o0 : o1);
            float sc = (which==0) ? QSCALE : 1.f;
            #pragma unroll
            for (int mt=0;mt<4;mt++)
              #pragma unroll
              for (int nt=0;nt<2;nt++) {
                int coll = (nblk & 1023) + wn*32 + nt*16 + l16;
                float bv = bs[coll];
                int h = coll >> 6, d = coll & 63;
                #pragma unroll
                for (int r=0;r<4;r++) {
                    int row = mblk + wm*64 + mt*16 + quad*4 + r;
                    int b = row >> 11, s = row & 2047;
                    O[((size_t)(b*NH + h)*SEQ + s)*HD + d] = f2bf((acc[mt][nt][r] + bv) * sc);
                }
              }
        } else {
            // V: padded LDS transpose (T[c][sp], stride 136 ushorts = 272B; 16B
            // aligned, rotates banks by 4 per col). tau-perm applied on the write
            // side: within each 32-row block, p = ((s>>2)&3)*8+((s>>4)&1)*4+(s&3).
            // Readback: fully-coalesced 16B/lane stores.
            unsigned short* T = lds;
            unsigned short* OV = (unsigned short*)o2;
            size_t rowbase = ((size_t)((mblk >> 11)*1024 + (nblk & 1023))) * SEQ + (mblk & 2047);
            __syncthreads();     // all K-loop LDS reads complete before overwrite
            #pragma unroll
            for (int nt=0;nt<2;nt++) {
                int cloc = wn*32 + nt*16 + l16;            // local col 0..127
                float bv = bs[(nblk & 1023) + cloc];
                #pragma unroll
                for (int mt=0;mt<4;mt++) {
                    int row0 = wm*64 + mt*16 + quad*4;     // local row, mult of 4
                    int sp0 = (row0 & ~31) | (((row0 >> 2) & 3) << 3) | (((row0 >> 4) & 1) << 2);
                    ushort4 w;
                    w.x = f2bf(acc[mt][nt][0] + bv);
                    w.y = f2bf(acc[mt][nt][1] + bv);
                    w.z = f2bf(acc[mt][nt][2] + bv);
                    w.w = f2bf(acc[mt][nt][3] + bv);
                    *(ushort4*)(T + cloc*136 + sp0) = w;
                }
            }
            __syncthreads();
            int s0 = (lane & 15) * 8, dloc = lane >> 4;    // 16 s-chunks x 4 cols
            #pragma unroll
            for (int i=0;i<4;i++) {
                int c = wave*16 + i*4 + dloc;              // local col 0..127
                short8 v = *(const short8*)(T + c*136 + s0);
                *(short8*)(OV + rowbase + (size_t)c * SEQ + s0) = v;
            }
        }
    }
}

// ---- kernel 4: flash attention, double-buffered LDS K/V staging with counted
// vmcnt (stage t+1 issued before computing t; vmcnt(1) leaves next stage in
// flight; raw s_barrier, never vmcnt(0) mid-loop). Register-only P; P->bf16
// pack via v_cvt_pk_bf16_f32 (replaces 5-op manual rounding per pair; RNE).
// S^T = mfma(A=K, B=Q) -> P^T in regs -> O^T = mfma(A=V^T, B=P^T).
__global__ __launch_bounds__(512, 4) void attn(
    const unsigned short* __restrict__ Q, const unsigned short* __restrict__ K,
    const unsigned short* __restrict__ VTp, unsigned short* __restrict__ O) {
    __shared__ unsigned short kv[2][4096];   // per buf: K tile [0,2048) + V tile [2048,4096)
    unsigned short* kvf = &kv[0][0];
    int tid = threadIdx.x;
    int lane = tid & 63, wave = tid >> 6;   // 8 waves
    int quad = lane >> 4, l16 = lane & 15;
    // 512 blocks: id = bh_low*64 + qblk*8 + xcd
    int id = blockIdx.x;
    int bh = (id & 7) * 8 + (id >> 6);
    int qblk = (id >> 3) & 7;
    int b = bh >> 4, h = bh & 15;
    int q0 = qblk * 256 + wave * 32;
    const unsigned short* Qb = Q + (size_t)bh * SEQ * HD;
    const unsigned short* Kb = K + (size_t)bh * SEQ * HD;
    const unsigned short* Vb = VTp + (size_t)bh * HD * SEQ;
    // staging source (per-lane, swizzled); LDS dest offset per wave
    int li = (wave & 3) * 64 + lane;            // 0..255 chunk index within K or V half
    const unsigned short* src;
    int dstofs = (wave & 3) * 512 + ((wave >> 2) ? 2048 : 0);
    int src_step;
    if (wave < 4) {
        int t = li >> 3, slot = li & 7;
        int dblk = slot ^ (t & 7);
        src = Kb + (size_t)t * HD + dblk * 8;
        src_step = 32 * HD;                      // t advances by 32
    } else {
        int d = li >> 2, slot = li & 3;
        int swz = (d & 3) ^ ((d >> 2) & 3);
        src = Vb + (size_t)d * SEQ + (slot ^ swz) * 8;
        src_step = 32;                           // t advances by 32
    }
    short8 qf[2][2];
    #pragma unroll
    for (int mt=0;mt<2;mt++) {
        const unsigned short* qp = Qb + (size_t)(q0 + mt*16 + l16) * HD + quad*8;
        qf[mt][0] = *(const short8*)(qp);
        qf[mt][1] = *(const short8*)(qp + 32);
    }
    floatx4 o_acc[2][4], l_acc[2];
    #pragma unroll
    for (int mt=0;mt<2;mt++) {
        l_acc[mt] = (floatx4){0.f,0.f,0.f,0.f};
        #pragma unroll
        for (int dt=0;dt<4;dt++) o_acc[mt][dt] = (floatx4){0.f,0.f,0.f,0.f};
    }
    short8 ones;
    #pragma unroll
    for (int jj=0;jj<8;jj++) ones[jj] = (short)0x3F80;   // bf16 1.0
    // precomputed swizzled LDS read offsets (ushort units, relative to buf base)
    int koff[2][2], voff[4];
    #pragma unroll
    for (int nt=0;nt<2;nt++) {
        int t = nt*16 + l16;
        #pragma unroll
        for (int hh=0;hh<2;hh++)
            koff[nt][hh] = t*64 + ((hh*4 + quad) ^ (t & 7)) * 8;
    }
    #pragma unroll
    for (int dt=0;dt<4;dt++) {
        int d = dt*16 + l16;
        voff[dt] = 2048 + d*32 + ((quad ^ (d & 3) ^ ((d >> 2) & 3))) * 8;
    }

    // prologue: stage tile 0 into buf 0
    load_lds16(src, kvf + dstofs);
    src += src_step;

    for (int it = 0; it < 64; ++it) {
        const unsigned short* kb = kvf + (it & 1) * 4096;
        if (it < 63) {
            load_lds16(src, kvf + ((it & 1) ^ 1) * 4096 + dstofs);
            src += src_step;
            asm volatile("s_waitcnt vmcnt(1)" ::: "memory");
        } else {
            asm volatile("s_waitcnt vmcnt(0)" ::: "memory");
        }
        __builtin_amdgcn_s_barrier();
        asm volatile("" ::: "memory");
        short8 kf[2][2], vf[4];
        #pragma unroll
        for (int nt=0;nt<2;nt++) {
            kf[nt][0] = *(const short8*)(kb + koff[nt][0]);
            kf[nt][1] = *(const short8*)(kb + koff[nt][1]);
        }
        #pragma unroll
        for (int dt=0;dt<4;dt++)
            vf[dt] = *(const short8*)(kb + voff[dt]);
        // S^T[t][q]: A = K rows (m = t), B = Q rows (n = q)
        floatx4 sacc[2][2];
        __builtin_amdgcn_s_setprio(1);
        #pragma unroll
        for (int nt=0;nt<2;nt++)
          #pragma unroll
          for (int mt=0;mt<2;mt++) {
            floatx4 s = (floatx4){0.f,0.f,0.f,0.f};
            s = __builtin_amdgcn_mfma_f32_16x16x32_bf16(kf[nt][0], qf[mt][0], s, 0, 0, 0);
            s = __builtin_amdgcn_mfma_f32_16x16x32_bf16(kf[nt][1], qf[mt][1], s, 0, 0, 0);
            sacc[nt][mt] = s;
          }
        __builtin_amdgcn_s_setprio(0);
        // P^T fragment in registers: slot j = nt*4 + r (matched by VT tau-perm);
        // pack two exp2 results per dword with v_cvt_pk_bf16_f32 (lo=src0, hi=src1)
        short8 pf[2];
        #pragma unroll
        for (int mt=0;mt<2;mt++) {
            uintx4 pu;
            #pragma unroll
            for (int jp=0;jp<4;jp++) {
                int nt = jp >> 1, rp = (jp & 1) * 2;
                float e0 = __builtin_amdgcn_exp2f(sacc[nt][mt][rp]);
                float e1 = __builtin_amdgcn_exp2f(sacc[nt][mt][rp+1]);
                unsigned int w;
                asm("v_cvt_pk_bf16_f32 %0, %1, %2" : "=v"(w) : "v"(e0), "v"(e1));
                pu[jp] = w;
            }
            pf[mt] = __builtin_bit_cast(short8, pu);
        }
        __builtin_amdgcn_s_setprio(1);
        #pragma unroll
        for (int mt=0;mt<2;mt++) {
            l_acc[mt] = __builtin_amdgcn_mfma_f32_16x16x32_bf16(ones, pf[mt], l_acc[mt], 0, 0, 0);
            #pragma unroll
            for (int dt=0;dt<4;dt++)
                o_acc[mt][dt] = __builtin_amdgcn_mfma_f32_16x16x32_bf16(vf[dt], pf[mt], o_acc[mt][dt], 0, 0, 0);
        }
        __builtin_amdgcn_s_setprio(0);
        asm volatile("" ::: "memory");
        __builtin_amdgcn_s_barrier();   // all reads of this buf done before next overwrite
    }
    // epilogue: o_acc[mt][dt][r] = O^T[d = dt*16+quad*4+r][q = mt*16+l16]; l replicated
    #pragma unroll
    for (int mt=0;mt<2;mt++) {
        float inv = 1.f / l_acc[mt][0];
        int s = q0 + mt*16 + l16;
        #pragma unroll
        for (int dt=0;dt<4;dt++) {
            ushort4 w;
            w.x = f2bf(o_acc[mt][dt][0]*inv);
            w.y = f2bf(o_acc[mt][dt][1]*inv);
            w.z = f2bf(o_acc[mt][dt][2]*inv);
            w.w = f2bf(o_acc[mt][dt][3]*inv);
            *(ushort4*)(O + ((size_t)b*SEQ + s)*EMBED + h*HD + dt*16 + quad*4) = w;
        }
    }
}

extern "C" void kernel_launch(void* const* d_in, const int* in_sizes, int n_in,
                              void* d_out, int out_size, void* d_ws, size_t ws_size,
                              hipStream_t stream) {
    const float* x  = (const float*)d_in[0];
    const float* Wq = (const float*)d_in[1]; const float* bq = (const float*)d_in[2];
    const float* Wk = (const float*)d_in[3]; const float* bk = (const float*)d_in[4];
    const float* Wv = (const float*)d_in[5]; const float* bv = (const float*)d_in[6];
    const float* Wo = (const float*)d_in[7]; const float* bo = (const float*)d_in[8];
    char* ws = (char*)d_ws;
    unsigned short* xb  = (unsigned short*)(ws);                      // 16 MB, reused as O later
    unsigned short* WqT = (unsigned short*)(ws + (16ull<<20));        // 2 MB each; Wq|Wk|Wv contiguous
    unsigned short* WkT = (unsigned short*)(ws + (18ull<<20));
    unsigned short* WvT = (unsigned short*)(ws + (20ull<<20));
    unsigned short* WoT = (unsigned short*)(ws + (22ull<<20));
    unsigned short* Qb  = (unsigned short*)(ws + (24ull<<20));        // 16 MB
    unsigned short* Kb  = (unsigned short*)(ws + (40ull<<20));        // 16 MB
    unsigned short* VTb = (unsigned short*)(ws + (56ull<<20));        // 16 MB  (total 72 MB)
    unsigned short* Ob  = xb;   // xb dead after QKV GEMM; reuse for attention output

    cvt_x<<<(M_TOT*EMBED)/1024, 256, 0, stream>>>(x, xb);
    wtrans<<<dim3(32,32,4), dim3(32,8), 0, stream>>>(Wq,Wk,Wv,Wo, WqT,WkT,WvT,WoT);
    // fused QKV: BT = WqT|WkT|WvT (contiguous), N = 3072 -> 64x24 = 1536 blocks,
    // 2 blocks/CU -> exactly 3 full passes
    gemmk<0><<<dim3(1536), 512, 0, stream>>>(xb, WqT, bq, bk, bv, Qb, Kb, VTb);
    attn<<<dim3(512), 512, 0, stream>>>(Qb, Kb, VTb, Ob);
    // out-proj: 64x8 = 512 blocks, 2 blocks/CU -> exactly 1 full pass
    gemmk<1><<<dim3(512), 512, 0, stream>>>(Ob, WoT, bo, bo, bo, (float*)d_out, nullptr, nullptr);
}